// Round 1
// baseline (44.845 us; speedup 1.0000x reference)
//
#include <hip/hip_runtime.h>

#define DEVFN __device__ __forceinline__

DEVFN float min3f(float a, float b, float c) { return fminf(fminf(a, b), c); }
DEVFN float max3f(float a, float b, float c) { return fmaxf(fmaxf(a, b), c); }
DEVFN float med3f(float a, float b, float c) {
    // median(a,b,c) = max(min(a,b), min(max(a,b), c))
    return fmaxf(fminf(a, b), fminf(fmaxf(a, b), c));
}

// Each thread computes 4 consecutive output pixels of one row.
// Column-sort decomposition: per shared column j (6 columns per thread),
// compute (min, med, max) of the 3 vertical taps; per output pixel use
// med3( max3(col mins), med3(col meds), min3(col maxes) ).
__global__ __launch_bounds__(256) void median3x3_kernel(
        const float* __restrict__ in, float* __restrict__ out,
        int H, int W, int rows_total) {
    const int groups_per_row = W >> 2;               // 128 for W=512
    int tid = blockIdx.x * blockDim.x + threadIdx.x;
    int r = tid / groups_per_row;
    if (r >= rows_total) return;
    int g = tid - r * groups_per_row;
    int x0 = g << 2;

    int y = r % H;                                    // row within image plane
    const float* rowm = in + (long)r * W;
    const bool has_top = (y > 0);
    const bool has_bot = (y < H - 1);
    const float* rowt = rowm - W;
    const float* rowb = rowm + W;

    float vt[6], vm[6], vb[6];

    // middle row (always valid)
    {
        float4 c = *reinterpret_cast<const float4*>(rowm + x0);
        vm[1] = c.x; vm[2] = c.y; vm[3] = c.z; vm[4] = c.w;
        vm[0] = (x0 > 0)     ? rowm[x0 - 1] : 0.0f;
        vm[5] = (x0 + 4 < W) ? rowm[x0 + 4] : 0.0f;
    }
    if (has_top) {
        float4 c = *reinterpret_cast<const float4*>(rowt + x0);
        vt[1] = c.x; vt[2] = c.y; vt[3] = c.z; vt[4] = c.w;
        vt[0] = (x0 > 0)     ? rowt[x0 - 1] : 0.0f;
        vt[5] = (x0 + 4 < W) ? rowt[x0 + 4] : 0.0f;
    } else {
        #pragma unroll
        for (int i = 0; i < 6; ++i) vt[i] = 0.0f;
    }
    if (has_bot) {
        float4 c = *reinterpret_cast<const float4*>(rowb + x0);
        vb[1] = c.x; vb[2] = c.y; vb[3] = c.z; vb[4] = c.w;
        vb[0] = (x0 > 0)     ? rowb[x0 - 1] : 0.0f;
        vb[5] = (x0 + 4 < W) ? rowb[x0 + 4] : 0.0f;
    } else {
        #pragma unroll
        for (int i = 0; i < 6; ++i) vb[i] = 0.0f;
    }

    // per-column vertical sort (min/med/max)
    float cmn[6], cmd[6], cmx[6];
    #pragma unroll
    for (int j = 0; j < 6; ++j) {
        cmn[j] = min3f(vt[j], vm[j], vb[j]);
        cmx[j] = max3f(vt[j], vm[j], vb[j]);
        cmd[j] = med3f(vt[j], vm[j], vb[j]);
    }

    float4 o;
    float* op = &o.x;
    #pragma unroll
    for (int i = 0; i < 4; ++i) {
        float lo = max3f(cmn[i], cmn[i + 1], cmn[i + 2]);
        float hi = min3f(cmx[i], cmx[i + 1], cmx[i + 2]);
        float mi = med3f(cmd[i], cmd[i + 1], cmd[i + 2]);
        op[i] = med3f(lo, mi, hi);
    }

    *reinterpret_cast<float4*>(out + (long)r * W + x0) = o;
}

extern "C" void kernel_launch(void* const* d_in, const int* in_sizes, int n_in,
                              void* d_out, int out_size, void* d_ws, size_t ws_size,
                              hipStream_t stream) {
    const float* noised = (const float*)d_in[0];
    const float* cover  = (const float*)d_in[1];
    float* out = (float*)d_out;

    const int H = 512, W = 512;
    const int n = in_sizes[0];                 // 16*3*512*512 = 12582912
    const int rows_total = n / W;              // B*C*H = 24576

    const int threads_total = rows_total * (W / 4);
    const int block = 256;
    const int grid = (threads_total + block - 1) / block;

    median3x3_kernel<<<grid, block, 0, stream>>>(noised, out, H, W, rows_total);

    // second tuple element: cover passed through unchanged
    hipMemcpyAsync(out + n, cover, (size_t)in_sizes[1] * sizeof(float),
                   hipMemcpyDeviceToDevice, stream);
}

// Round 2
// 42.316 us; speedup vs baseline: 1.0598x; 1.0598x over previous
//
#include <hip/hip_runtime.h>

#define DEVFN __device__ __forceinline__

DEVFN float min3f(float a, float b, float c) { return fminf(fminf(a, b), c); }
DEVFN float max3f(float a, float b, float c) { return fmaxf(fmaxf(a, b), c); }
DEVFN float med3f(float a, float b, float c) {
    // median(a,b,c) = max(min(a,b), min(max(a,b), c))
    return fmaxf(fminf(a, b), fminf(fmaxf(a, b), c));
}

// Fixed problem shape: 16 x 3 x 512 x 512 f32.
// Each thread: 4 consecutive output pixels of one row (3x3 median, zero pad)
// PLUS the matching float4 pass-through copy of `cover` -> out + n.
// Column-sort decomposition: per shared column j (6 per thread) compute
// (min, med, max) of the 3 vertical taps; output = med3(max3(mins),
// med3(meds), min3(maxes)).
__global__ __launch_bounds__(256) void median3x3_fused(
        const float* __restrict__ in, const float* __restrict__ cover,
        float* __restrict__ out, float* __restrict__ out2) {
    constexpr int W = 512;
    constexpr int H = 512;
    constexpr int GPR_LOG2 = 7;                 // 512/4 = 128 groups per row

    int tid = blockIdx.x * blockDim.x + threadIdx.x;
    int r = tid >> GPR_LOG2;                    // global row in [0, B*C*H)
    int g = tid & ((1 << GPR_LOG2) - 1);
    int x0 = g << 2;
    long base = ((long)r << 9) + x0;            // r*W + x0

    // ---- pass-through copy of cover (independent, issues early) ----
    float4 cv = *reinterpret_cast<const float4*>(cover + base);

    int y = r & (H - 1);                        // row within image plane
    const float* rowm = in + ((long)r << 9);
    const bool has_top = (y > 0);
    const bool has_bot = (y < H - 1);
    const float* rowt = rowm - W;
    const float* rowb = rowm + W;

    float vt[6], vm[6], vb[6];

    {
        float4 c = *reinterpret_cast<const float4*>(rowm + x0);
        vm[1] = c.x; vm[2] = c.y; vm[3] = c.z; vm[4] = c.w;
        vm[0] = (x0 > 0)     ? rowm[x0 - 1] : 0.0f;
        vm[5] = (x0 + 4 < W) ? rowm[x0 + 4] : 0.0f;
    }
    if (has_top) {
        float4 c = *reinterpret_cast<const float4*>(rowt + x0);
        vt[1] = c.x; vt[2] = c.y; vt[3] = c.z; vt[4] = c.w;
        vt[0] = (x0 > 0)     ? rowt[x0 - 1] : 0.0f;
        vt[5] = (x0 + 4 < W) ? rowt[x0 + 4] : 0.0f;
    } else {
        #pragma unroll
        for (int i = 0; i < 6; ++i) vt[i] = 0.0f;
    }
    if (has_bot) {
        float4 c = *reinterpret_cast<const float4*>(rowb + x0);
        vb[1] = c.x; vb[2] = c.y; vb[3] = c.z; vb[4] = c.w;
        vb[0] = (x0 > 0)     ? rowb[x0 - 1] : 0.0f;
        vb[5] = (x0 + 4 < W) ? rowb[x0 + 4] : 0.0f;
    } else {
        #pragma unroll
        for (int i = 0; i < 6; ++i) vb[i] = 0.0f;
    }

    // per-column vertical sort (min/med/max)
    float cmn[6], cmd[6], cmx[6];
    #pragma unroll
    for (int j = 0; j < 6; ++j) {
        cmn[j] = min3f(vt[j], vm[j], vb[j]);
        cmx[j] = max3f(vt[j], vm[j], vb[j]);
        cmd[j] = med3f(vt[j], vm[j], vb[j]);
    }

    float4 o;
    float* op = &o.x;
    #pragma unroll
    for (int i = 0; i < 4; ++i) {
        float lo = max3f(cmn[i], cmn[i + 1], cmn[i + 2]);
        float hi = min3f(cmx[i], cmx[i + 1], cmx[i + 2]);
        float mi = med3f(cmd[i], cmd[i + 1], cmd[i + 2]);
        op[i] = med3f(lo, mi, hi);
    }

    *reinterpret_cast<float4*>(out + base) = o;
    *reinterpret_cast<float4*>(out2 + base) = cv;
}

extern "C" void kernel_launch(void* const* d_in, const int* in_sizes, int n_in,
                              void* d_out, int out_size, void* d_ws, size_t ws_size,
                              hipStream_t stream) {
    const float* noised = (const float*)d_in[0];
    const float* cover  = (const float*)d_in[1];
    float* out = (float*)d_out;

    const int n = in_sizes[0];                 // 16*3*512*512 = 12582912
    const int rows_total = n / 512;            // 24576
    const int threads_total = rows_total * (512 / 4);
    const int block = 256;
    const int grid = threads_total / block;    // 12288

    median3x3_fused<<<grid, block, 0, stream>>>(noised, cover, out, out + n);
}

// Round 3
// 36.500 us; speedup vs baseline: 1.2286x; 1.1593x over previous
//
#include <hip/hip_runtime.h>

#define DEVFN __device__ __forceinline__

DEVFN float min3f(float a, float b, float c) { return fminf(fminf(a, b), c); }
DEVFN float max3f(float a, float b, float c) { return fmaxf(fmaxf(a, b), c); }
DEVFN float med3f(float a, float b, float c) {
    return fmaxf(fminf(a, b), fminf(fmaxf(a, b), c));
}

// Fixed shape: 16 x 3 x 512 x 512 f32, 3x3 median with zero padding,
// plus pass-through copy of `cover` into out+n.
// Each thread: a 4-row x 4-col output tile. Loads 6 input rows (float4 +
// 2 halo scalars each) into registers once -> vertical reuse in registers,
// 10 independent float4 loads issued up-front for MLP.
__global__ __launch_bounds__(256) void median3x3_r4(
        const float* __restrict__ in, const float* __restrict__ cover,
        float* __restrict__ out, float* __restrict__ out2) {
    constexpr int W = 512;
    constexpr int H = 512;

    int tid = blockIdx.x * blockDim.x + threadIdx.x;
    int rg  = tid >> 7;                 // row-group id, 4 rows each
    int g   = tid & 127;                // horizontal group
    int x0  = g << 2;
    int plane = rg >> 7;                // 128 row-groups per 512-row plane
    int y0  = (rg & 127) << 2;          // first output row in plane

    int rbase = (plane << 18) + (y0 << 9) + x0;   // element index of (y0, x0)
    const float* rowp = in + rbase;                // points at (y0, x0)

    // v[0] = row y0-1 (halo), v[1..4] = rows y0..y0+3, v[5] = row y0+4 (halo)
    float v[6][6];

    // interior rows — always valid, issue first for MLP
    #pragma unroll
    for (int t = 0; t < 4; ++t) {
        const float* rp = rowp + (t << 9);
        float4 c = *reinterpret_cast<const float4*>(rp);
        v[t + 1][1] = c.x; v[t + 1][2] = c.y; v[t + 1][3] = c.z; v[t + 1][4] = c.w;
        v[t + 1][0] = (x0 > 0)     ? rp[-1] : 0.0f;
        v[t + 1][5] = (x0 + 4 < W) ? rp[4]  : 0.0f;
    }
    if (y0 > 0) {
        const float* rp = rowp - W;
        float4 c = *reinterpret_cast<const float4*>(rp);
        v[0][1] = c.x; v[0][2] = c.y; v[0][3] = c.z; v[0][4] = c.w;
        v[0][0] = (x0 > 0)     ? rp[-1] : 0.0f;
        v[0][5] = (x0 + 4 < W) ? rp[4]  : 0.0f;
    } else {
        #pragma unroll
        for (int j = 0; j < 6; ++j) v[0][j] = 0.0f;
    }
    if (y0 + 4 < H) {
        const float* rp = rowp + (4 << 9);
        float4 c = *reinterpret_cast<const float4*>(rp);
        v[5][1] = c.x; v[5][2] = c.y; v[5][3] = c.z; v[5][4] = c.w;
        v[5][0] = (x0 > 0)     ? rp[-1] : 0.0f;
        v[5][5] = (x0 + 4 < W) ? rp[4]  : 0.0f;
    } else {
        #pragma unroll
        for (int j = 0; j < 6; ++j) v[5][j] = 0.0f;
    }

    // cover pass-through (independent loads, overlap with median compute)
    float4 cv[4];
    #pragma unroll
    for (int t = 0; t < 4; ++t)
        cv[t] = *reinterpret_cast<const float4*>(cover + rbase + (t << 9));

    #pragma unroll
    for (int t = 0; t < 4; ++t) {
        float cmn[6], cmd[6], cmx[6];
        #pragma unroll
        for (int j = 0; j < 6; ++j) {
            float a = v[t][j], b = v[t + 1][j], c = v[t + 2][j];
            cmn[j] = min3f(a, b, c);
            cmx[j] = max3f(a, b, c);
            cmd[j] = med3f(a, b, c);
        }
        float4 o;
        float* op = &o.x;
        #pragma unroll
        for (int i = 0; i < 4; ++i) {
            float lo = max3f(cmn[i], cmn[i + 1], cmn[i + 2]);
            float hi = min3f(cmx[i], cmx[i + 1], cmx[i + 2]);
            float mi = med3f(cmd[i], cmd[i + 1], cmd[i + 2]);
            op[i] = med3f(lo, mi, hi);
        }
        *reinterpret_cast<float4*>(out  + rbase + (t << 9)) = o;
        *reinterpret_cast<float4*>(out2 + rbase + (t << 9)) = cv[t];
    }
}

extern "C" void kernel_launch(void* const* d_in, const int* in_sizes, int n_in,
                              void* d_out, int out_size, void* d_ws, size_t ws_size,
                              hipStream_t stream) {
    const float* noised = (const float*)d_in[0];
    const float* cover  = (const float*)d_in[1];
    float* out = (float*)d_out;

    const int n = in_sizes[0];                  // 16*3*512*512 = 12582912
    const int rows_total = n / 512;             // 24576
    const int row_groups = rows_total / 4;      // 6144
    const int threads_total = row_groups * 128; // 786432
    const int block = 256;
    const int grid = threads_total / block;     // 3072

    median3x3_r4<<<grid, block, 0, stream>>>(noised, cover, out, out + n);
}

// Round 4
// 34.011 us; speedup vs baseline: 1.3185x; 1.0732x over previous
//
#include <hip/hip_runtime.h>

#define DEVFN __device__ __forceinline__

typedef float f32x4 __attribute__((ext_vector_type(4)));

DEVFN float min3f(float a, float b, float c) { return fminf(fminf(a, b), c); }
DEVFN float max3f(float a, float b, float c) { return fmaxf(fmaxf(a, b), c); }
DEVFN float med3f(float a, float b, float c) {
    return fmaxf(fminf(a, b), fminf(fmaxf(a, b), c));
}

// Fixed shape: 16 x 3 x 512 x 512 f32, 3x3 median with zero padding,
// plus pass-through copy of `cover` into out+n.
// Each thread: 4-row x 4-col output tile (6 input rows in registers).
// XCD-aware chunked blockIdx swizzle: adjacent row-bands land on the SAME
// XCD so halo rows hit that XCD's L2 instead of re-fetching from HBM.
// Outputs stored non-temporally (never re-read; keep L2 for input halos).
__global__ __launch_bounds__(256) void median3x3_r4_swz(
        const float* __restrict__ in, const float* __restrict__ cover,
        float* __restrict__ out, float* __restrict__ out2, int chunk) {
    constexpr int W = 512;
    constexpr int H = 512;

    // bijective chunked XCD swizzle (grid % 8 == 0)
    int bid = blockIdx.x;
    int swz = (bid & 7) * chunk + (bid >> 3);
    int tid = swz * blockDim.x + threadIdx.x;

    int rg  = tid >> 7;                 // row-band id, 4 rows each
    int g   = tid & 127;                // horizontal group
    int x0  = g << 2;
    int plane = rg >> 7;                // 128 row-bands per 512-row plane
    int y0  = (rg & 127) << 2;          // first output row in plane

    int rbase = (plane << 18) + (y0 << 9) + x0;   // element index of (y0, x0)
    const float* rowp = in + rbase;

    // v[0] = row y0-1 (halo), v[1..4] = rows y0..y0+3, v[5] = row y0+4 (halo)
    float v[6][6];

    #pragma unroll
    for (int t = 0; t < 4; ++t) {
        const float* rp = rowp + (t << 9);
        f32x4 c = *reinterpret_cast<const f32x4*>(rp);
        v[t + 1][1] = c.x; v[t + 1][2] = c.y; v[t + 1][3] = c.z; v[t + 1][4] = c.w;
        v[t + 1][0] = (x0 > 0)     ? rp[-1] : 0.0f;
        v[t + 1][5] = (x0 + 4 < W) ? rp[4]  : 0.0f;
    }
    if (y0 > 0) {
        const float* rp = rowp - W;
        f32x4 c = *reinterpret_cast<const f32x4*>(rp);
        v[0][1] = c.x; v[0][2] = c.y; v[0][3] = c.z; v[0][4] = c.w;
        v[0][0] = (x0 > 0)     ? rp[-1] : 0.0f;
        v[0][5] = (x0 + 4 < W) ? rp[4]  : 0.0f;
    } else {
        #pragma unroll
        for (int j = 0; j < 6; ++j) v[0][j] = 0.0f;
    }
    if (y0 + 4 < H) {
        const float* rp = rowp + (4 << 9);
        f32x4 c = *reinterpret_cast<const f32x4*>(rp);
        v[5][1] = c.x; v[5][2] = c.y; v[5][3] = c.z; v[5][4] = c.w;
        v[5][0] = (x0 > 0)     ? rp[-1] : 0.0f;
        v[5][5] = (x0 + 4 < W) ? rp[4]  : 0.0f;
    } else {
        #pragma unroll
        for (int j = 0; j < 6; ++j) v[5][j] = 0.0f;
    }

    // cover pass-through (independent loads, overlap with median compute)
    f32x4 cv[4];
    #pragma unroll
    for (int t = 0; t < 4; ++t)
        cv[t] = *reinterpret_cast<const f32x4*>(cover + rbase + (t << 9));

    #pragma unroll
    for (int t = 0; t < 4; ++t) {
        float cmn[6], cmd[6], cmx[6];
        #pragma unroll
        for (int j = 0; j < 6; ++j) {
            float a = v[t][j], b = v[t + 1][j], c = v[t + 2][j];
            cmn[j] = min3f(a, b, c);
            cmx[j] = max3f(a, b, c);
            cmd[j] = med3f(a, b, c);
        }
        f32x4 o;
        #pragma unroll
        for (int i = 0; i < 4; ++i) {
            float lo = max3f(cmn[i], cmn[i + 1], cmn[i + 2]);
            float hi = min3f(cmx[i], cmx[i + 1], cmx[i + 2]);
            float mi = med3f(cmd[i], cmd[i + 1], cmd[i + 2]);
            o[i] = med3f(lo, mi, hi);
        }
        __builtin_nontemporal_store(o,     reinterpret_cast<f32x4*>(out  + rbase + (t << 9)));
        __builtin_nontemporal_store(cv[t], reinterpret_cast<f32x4*>(out2 + rbase + (t << 9)));
    }
}

extern "C" void kernel_launch(void* const* d_in, const int* in_sizes, int n_in,
                              void* d_out, int out_size, void* d_ws, size_t ws_size,
                              hipStream_t stream) {
    const float* noised = (const float*)d_in[0];
    const float* cover  = (const float*)d_in[1];
    float* out = (float*)d_out;

    const int n = in_sizes[0];                  // 16*3*512*512 = 12582912
    const int rows_total = n / 512;             // 24576
    const int row_groups = rows_total / 4;      // 6144
    const int threads_total = row_groups * 128; // 786432
    const int block = 256;
    const int grid = threads_total / block;     // 3072 (divisible by 8)
    const int chunk = grid / 8;                 // 384

    median3x3_r4_swz<<<grid, block, 0, stream>>>(noised, cover, out, out + n, chunk);
}